// Round 1
// baseline (3181.021 us; speedup 1.0000x reference)
//
#include <hip/hip_runtime.h>
#include <math.h>

#define B_   64
#define T_   128
#define NIN  256
#define H_   512
#define O_   256
#define M_   64
#define R_   512
#define EPS_ 1e-8f

__device__ __forceinline__ float dot4(float4 a, float4 b) {
    return a.x*b.x + a.y*b.y + a.z*b.z + a.w*b.w;
}

// 16-lane (DPP-row) sum reduction: quad_perm xor1, xor2, row_ror:4, row_ror:8.
// Leaves the full 16-lane sum in ALL 16 lanes.
template<int CTRL>
__device__ __forceinline__ float dpp_add(float v) {
    int t = __builtin_amdgcn_update_dpp(0, __float_as_int(v), CTRL, 0xF, 0xF, false);
    return v + __int_as_float(t);
}
__device__ __forceinline__ float red16(float v) {
    v = dpp_add<0xB1>(v);    // quad_perm [1,0,3,2]  (xor 1)
    v = dpp_add<0x4E>(v);    // quad_perm [2,3,0,1]  (xor 2)
    v = dpp_add<0x124>(v);   // row_ror:4
    v = dpp_add<0x128>(v);   // row_ror:8
    return v;
}
__device__ __forceinline__ float red64(float v) {
    v = red16(v);
    v += __shfl_xor(v, 16, 64);
    v += __shfl_xor(v, 32, 64);
    return v;
}
__device__ __forceinline__ float sigmoidf_(float x) { return 1.f / (1.f + expf(-x)); }
__device__ __forceinline__ float softplusf_(float x) { return x > 20.f ? x : log1pf(expf(x)); }

// ---------------- Kernel 1: xin[bt][i] = x[bt] @ W_in.T + b_in ----------------
__global__ __launch_bounds__(256) void xin_gemm(
    const float* __restrict__ x, const float* __restrict__ Win,
    const float* __restrict__ bin, float* __restrict__ xin)
{
    __shared__ __align__(16) float xs[32 * NIN];   // 32 KB
    const int tid  = threadIdx.x;
    const int row0 = blockIdx.x * 32;

    #pragma unroll
    for (int i = 0; i < 8; ++i) {
        int idx = i * 1024 + tid * 4;
        *(float4*)&xs[idx] = *(const float4*)&x[(size_t)row0 * NIN + idx];
    }
    __syncthreads();

    const int rg = tid >> 6;      // 4 row-groups of 8 rows
    const int cg = tid & 63;      // 64 col-groups of 8 cols
    const int c0 = cg * 8;
    float acc[8][8];
    #pragma unroll
    for (int r = 0; r < 8; ++r)
        #pragma unroll
        for (int c = 0; c < 8; ++c) acc[r][c] = 0.f;

    for (int k = 0; k < NIN; k += 4) {
        float4 xq[8];
        #pragma unroll
        for (int r = 0; r < 8; ++r) xq[r] = *(float4*)&xs[(rg * 8 + r) * NIN + k];
        #pragma unroll
        for (int c = 0; c < 8; ++c) {
            float4 w4 = *(const float4*)&Win[(size_t)(c0 + c) * NIN + k];
            #pragma unroll
            for (int r = 0; r < 8; ++r) acc[r][c] += dot4(xq[r], w4);
        }
    }
    #pragma unroll
    for (int r = 0; r < 8; ++r) {
        int grow = row0 + rg * 8 + r;
        #pragma unroll
        for (int c = 0; c < 8; ++c)
            xin[(size_t)grow * H_ + c0 + c] = acc[r][c] + bin[c0 + c];
    }
}

// ---------------- Kernel 2: the recurrent loop, one WG per batch element ----------------
__global__ __launch_bounds__(1024) void ntm_loop(
    const float* __restrict__ xin,
    const float* __restrict__ h0,
    const float* __restrict__ frf0, const float* __restrict__ fwf0,
    const float* __restrict__ m0,
    const float* __restrict__ Wkr, const float* __restrict__ bkr_g,
    const float* __restrict__ Wbr, const float* __restrict__ bbr_g,
    const float* __restrict__ Wgr, const float* __restrict__ bgr_g,
    const float* __restrict__ Wkw, const float* __restrict__ bkw_g,
    const float* __restrict__ Wbw, const float* __restrict__ bbw_g,
    const float* __restrict__ Wgw, const float* __restrict__ bgw_g,
    const float* __restrict__ We,  const float* __restrict__ be_g,
    const float* __restrict__ Wa,  const float* __restrict__ ba_g,
    const float* __restrict__ Wread, const float* __restrict__ bread_g,
    float* __restrict__ h_all)
{
    __shared__ __align__(16) float mem[R_ * M_];     // 128 KB
    __shared__ __align__(16) float hbuf[H_];
    __shared__ float frf2[2][R_];
    __shared__ float fwf2[2][R_];
    __shared__ float dotsR[R_];                      // aliased as exp() after P3a
    __shared__ float dotsW[R_];
    __shared__ float nrm2[R_];
    __shared__ float wread_s[R_];
    __shared__ float wwrite_s[R_];
    __shared__ __align__(16) float kR[M_];
    __shared__ __align__(16) float kW[M_];
    __shared__ __align__(16) float eV[M_];
    __shared__ __align__(16) float aV[M_];
    __shared__ __align__(16) float rt[M_];
    __shared__ float wsumR[8], wsumW[8];
    __shared__ float bias4[4 * M_];
    __shared__ float scal[8];   // 0:beta_r 1:g_r 2:beta_w 3:g_w 4:kkR 5:kkW

    const int b    = blockIdx.x;
    const int tid  = threadIdx.x;
    const int wave = tid >> 6, lane = tid & 63;
    const int g    = lane >> 4, sub = lane & 15;

    // ---- init: stage state ----
    const float* mg = m0 + (size_t)b * (R_ * M_);
    #pragma unroll
    for (int i = 0; i < 8; ++i) {
        int idx = i * 4096 + tid * 4;
        *(float4*)&mem[idx] = *(const float4*)&mg[idx];
    }
    if (tid < H_) hbuf[tid] = h0[b * H_ + tid];
    if (tid < R_) { frf2[0][tid] = frf0[b * R_ + tid]; fwf2[0][tid] = fwf0[b * R_ + tid]; }
    if (tid < M_) {
        bias4[tid]          = bkr_g[tid];
        bias4[M_ + tid]     = bkw_g[tid];
        bias4[2 * M_ + tid] = be_g[tid];
        bias4[3 * M_ + tid] = ba_g[tid];
    }
    __syncthreads();
    // initial row norms (sum of squares)
    #pragma unroll
    for (int i = 0; i < 8; ++i) {
        int r = wave * 32 + i * 4 + g;
        float4 v = *(float4*)&mem[r * M_ + sub * 4];
        float np = v.x*v.x + v.y*v.y + v.z*v.z + v.w*v.w;
        np = red16(np);
        if (sub == 0) nrm2[r] = np;
    }
    __syncthreads();

    for (int t = 0; t < T_; ++t) {
        const int cur = t & 1, nxt = cur ^ 1;

        // ---- P1: controller projections k_r,k_w,e,a (+ beta/g scalars) ----
        {
            const int row = tid >> 4, s16 = tid & 15;
            float a0 = 0, a1 = 0, a2 = 0, a3 = 0;
            const float* p0 = Wkr + row * H_ + s16 * 32;
            const float* p1 = Wkw + row * H_ + s16 * 32;
            const float* p2 = We  + row * H_ + s16 * 32;
            const float* p3 = Wa  + row * H_ + s16 * 32;
            #pragma unroll
            for (int j = 0; j < 8; ++j) {
                float4 h4 = *(float4*)&hbuf[s16 * 32 + j * 4];
                a0 += dot4(h4, *(const float4*)&p0[j * 4]);
                a1 += dot4(h4, *(const float4*)&p1[j * 4]);
                a2 += dot4(h4, *(const float4*)&p2[j * 4]);
                a3 += dot4(h4, *(const float4*)&p3[j * 4]);
            }
            a0 = red16(a0); a1 = red16(a1); a2 = red16(a2); a3 = red16(a3);
            if      (s16 == 0) kR[row] = tanhf(a0 + bias4[row]);
            else if (s16 == 1) kW[row] = tanhf(a1 + bias4[M_ + row]);
            else if (s16 == 2) eV[row] = sigmoidf_(a2 + bias4[2 * M_ + row]);
            else if (s16 == 3) aV[row] = tanhf(a3 + bias4[3 * M_ + row]);

            if (tid < 256) {   // waves 0..3: the 4 scalar heads
                const int sc = tid >> 6;
                const float* Ws = sc == 0 ? Wbr : sc == 1 ? Wgr : sc == 2 ? Wbw : Wgw;
                const float* bs = sc == 0 ? bbr_g : sc == 1 ? bgr_g : sc == 2 ? bbw_g : bgw_g;
                float acc = 0;
                #pragma unroll
                for (int j = 0; j < 2; ++j) {
                    float4 h4 = *(float4*)&hbuf[lane * 8 + j * 4];
                    acc += dot4(h4, *(const float4*)&Ws[lane * 8 + j * 4]);
                }
                acc = red64(acc);
                if (lane == 0) {
                    float xv = acc + bs[0];
                    scal[sc] = (sc == 0 || sc == 2) ? softplusf_(xv) : sigmoidf_(xv);
                }
            }
        }
        __syncthreads();   // B1

        // ---- P2: content dots against pre-update memory ----
        {
            float4 kr4 = *(float4*)&kR[sub * 4];
            float4 kw4 = *(float4*)&kW[sub * 4];
            #pragma unroll
            for (int i = 0; i < 8; ++i) {
                int r = wave * 32 + i * 4 + g;
                float4 v = *(float4*)&mem[r * M_ + sub * 4];
                float dr = red16(dot4(kr4, v));
                float dw = red16(dot4(kw4, v));
                if      (sub == 0) dotsR[r] = dr;
                else if (sub == 1) dotsW[r] = dw;
            }
            if (wave == 15) {   // ||k||^2 for both keys
                float q = kR[lane];  float s  = red64(q * q);
                if (lane == 0) scal[4] = s;
                float q2 = kW[lane]; float s2 = red64(q2 * q2);
                if (lane == 0) scal[5] = s2;
            }
        }
        __syncthreads();   // B2

        // ---- P3a: scores -> exp (max-free, scores are beta*cos-sim, bounded) ----
        if (tid < R_) {
            const int r = tid;
            float sn = sqrtf(nrm2[r]);
            float dR = sqrtf(scal[4]) * sn + EPS_;
            float dW = sqrtf(scal[5]) * sn + EPS_;
            float eR = expf(scal[0] * dotsR[r] / dR);
            float eW = expf(scal[2] * dotsW[r] / dW);
            dotsR[r] = eR; dotsW[r] = eW;
            float s1 = red64(eR);
            float s2 = red64(eW);
            if (lane == 0) { wsumR[wave] = s1; wsumW[wave] = s2; }
        } else if (tid < R_ + M_) {
            rt[tid - R_] = 0.f;
        }
        __syncthreads();   // B3

        // ---- P3b: softmax finalize + filter update + 3-tap smooth (local recompute) ----
        if (tid < R_) {
            const int r = tid;
            float totR = 0, totW = 0;
            #pragma unroll
            for (int w = 0; w < 8; ++w) { totR += wsumR[w]; totW += wsumW[w]; }
            float invR = 1.f / totR, invW = 1.f / totW;
            const int rm = (r + R_ - 1) & (R_ - 1), rp = (r + 1) & (R_ - 1);
            float gr = scal[1], gw = scal[3];

            float f0 = gr * dotsR[r]  * invR + (1.f - gr) * frf2[cur][r];
            float fm = gr * dotsR[rm] * invR + (1.f - gr) * frf2[cur][rm];
            float fp = gr * dotsR[rp] * invR + (1.f - gr) * frf2[cur][rp];
            frf2[nxt][r] = f0;
            wread_s[r] = 0.5f * f0 + 0.5f * (0.25f * fm + 0.5f * f0 + 0.25f * fp);

            float q0 = gw * dotsW[r]  * invW + (1.f - gw) * fwf2[cur][r];
            float qm = gw * dotsW[rm] * invW + (1.f - gw) * fwf2[cur][rm];
            float qp = gw * dotsW[rp] * invW + (1.f - gw) * fwf2[cur][rp];
            fwf2[nxt][r] = q0;
            wwrite_s[r] = 0.5f * q0 + 0.5f * (0.25f * qm + 0.5f * q0 + 0.25f * qp);
        }
        __syncthreads();   // B4

        // ---- P4: fused r_t + erase/add update + next-step norms ----
        {
            float4 e4 = *(float4*)&eV[sub * 4];
            float4 a4 = *(float4*)&aV[sub * 4];
            float rt0 = 0, rt1 = 0, rt2 = 0, rt3 = 0;
            #pragma unroll
            for (int i = 0; i < 8; ++i) {
                int r = wave * 32 + i * 4 + g;
                float wr = wread_s[r], ww = wwrite_s[r];
                float4 v = *(float4*)&mem[r * M_ + sub * 4];
                rt0 += wr * v.x; rt1 += wr * v.y; rt2 += wr * v.z; rt3 += wr * v.w;
                float4 nv;
                nv.x = v.x * (1.f - ww * e4.x) + ww * a4.x;
                nv.y = v.y * (1.f - ww * e4.y) + ww * a4.y;
                nv.z = v.z * (1.f - ww * e4.z) + ww * a4.z;
                nv.w = v.w * (1.f - ww * e4.w) + ww * a4.w;
                *(float4*)&mem[r * M_ + sub * 4] = nv;
                float np = nv.x*nv.x + nv.y*nv.y + nv.z*nv.z + nv.w*nv.w;
                np = red16(np);
                if (sub == 0) nrm2[r] = np;
            }
            rt0 += __shfl_xor(rt0, 16, 64); rt0 += __shfl_xor(rt0, 32, 64);
            rt1 += __shfl_xor(rt1, 16, 64); rt1 += __shfl_xor(rt1, 32, 64);
            rt2 += __shfl_xor(rt2, 16, 64); rt2 += __shfl_xor(rt2, 32, 64);
            rt3 += __shfl_xor(rt3, 16, 64); rt3 += __shfl_xor(rt3, 32, 64);
            if (g == 0) {
                atomicAdd(&rt[sub * 4 + 0], rt0);
                atomicAdd(&rt[sub * 4 + 1], rt1);
                atomicAdd(&rt[sub * 4 + 2], rt2);
                atomicAdd(&rt[sub * 4 + 3], rt3);
            }
        }
        __syncthreads();   // B5

        // ---- P6: h_{t+1} = relu(xin + W_read @ r_t + b_read) ----
        if (tid < H_) {
            const int i = tid;
            float acc = bread_g[i];
            const float* wr = Wread + i * M_;
            #pragma unroll
            for (int j = 0; j < 16; ++j)
                acc += dot4(*(const float4*)&wr[j * 4], *(float4*)&rt[j * 4]);
            acc += xin[(size_t)(b * T_ + t) * H_ + i];
            float hv = fmaxf(acc, 0.f);
            hbuf[i] = hv;
            h_all[(size_t)(b * T_ + t) * H_ + i] = hv;
        }
        __syncthreads();   // B6
    }
}

// ---------------- Kernel 3: out[bt][o] = sigmoid(h_all[bt] @ W_out.T + b_out) ----------------
__global__ __launch_bounds__(256) void out_gemm(
    const float* __restrict__ h_all, const float* __restrict__ Wout,
    const float* __restrict__ bout, float* __restrict__ out)
{
    __shared__ __align__(16) float hs[32 * H_];   // 64 KB
    const int tid  = threadIdx.x;
    const int row0 = blockIdx.x * 32;

    #pragma unroll
    for (int i = 0; i < 16; ++i) {
        int idx = i * 1024 + tid * 4;
        *(float4*)&hs[idx] = *(const float4*)&h_all[(size_t)row0 * H_ + idx];
    }
    __syncthreads();

    const int rg = tid >> 6;     // 4 row-groups of 8 rows
    const int cg = tid & 63;     // 64 col-groups of 4 cols
    const int c0 = cg * 4;
    float acc[8][4];
    #pragma unroll
    for (int r = 0; r < 8; ++r)
        #pragma unroll
        for (int c = 0; c < 4; ++c) acc[r][c] = 0.f;

    for (int k = 0; k < H_; k += 4) {
        float4 xq[8];
        #pragma unroll
        for (int r = 0; r < 8; ++r) xq[r] = *(float4*)&hs[(rg * 8 + r) * H_ + k];
        #pragma unroll
        for (int c = 0; c < 4; ++c) {
            float4 w4 = *(const float4*)&Wout[(size_t)(c0 + c) * H_ + k];
            #pragma unroll
            for (int r = 0; r < 8; ++r) acc[r][c] += dot4(xq[r], w4);
        }
    }
    #pragma unroll
    for (int r = 0; r < 8; ++r) {
        int grow = row0 + rg * 8 + r;
        float4 o4;
        o4.x = sigmoidf_(acc[r][0] + bout[c0 + 0]);
        o4.y = sigmoidf_(acc[r][1] + bout[c0 + 1]);
        o4.z = sigmoidf_(acc[r][2] + bout[c0 + 2]);
        o4.w = sigmoidf_(acc[r][3] + bout[c0 + 3]);
        *(float4*)&out[(size_t)grow * O_ + c0] = o4;
    }
}

extern "C" void kernel_launch(void* const* d_in, const int* in_sizes, int n_in,
                              void* d_out, int out_size, void* d_ws, size_t ws_size,
                              hipStream_t stream) {
    const float* x     = (const float*)d_in[0];
    const float* h0    = (const float*)d_in[1];
    const float* frf   = (const float*)d_in[2];
    // d_in[3] (wrf) dead state in reference
    const float* fwf   = (const float*)d_in[4];
    // d_in[5] (wwf) dead state in reference
    const float* m0    = (const float*)d_in[6];
    const float* Win   = (const float*)d_in[7];
    const float* bin   = (const float*)d_in[8];
    const float* Wread = (const float*)d_in[9];
    const float* bread = (const float*)d_in[10];
    const float* Wout  = (const float*)d_in[11];
    const float* bout  = (const float*)d_in[12];
    const float* Wkr   = (const float*)d_in[13];
    const float* bkr   = (const float*)d_in[14];
    const float* Wbr   = (const float*)d_in[15];
    const float* bbr   = (const float*)d_in[16];
    const float* Wgr   = (const float*)d_in[17];
    const float* bgr   = (const float*)d_in[18];
    const float* Wkw   = (const float*)d_in[19];
    const float* bkw   = (const float*)d_in[20];
    const float* Wbw   = (const float*)d_in[21];
    const float* bbw   = (const float*)d_in[22];
    const float* Wgw   = (const float*)d_in[23];
    const float* bgw   = (const float*)d_in[24];
    const float* We    = (const float*)d_in[25];
    const float* be    = (const float*)d_in[26];
    const float* Wa    = (const float*)d_in[27];
    const float* ba    = (const float*)d_in[28];

    float* xin   = (float*)d_ws;                                        // B*T*H f32 = 16 MB
    float* h_all = (float*)((char*)d_ws + (size_t)B_ * T_ * H_ * 4);    // 16 MB

    xin_gemm<<<256, 256, 0, stream>>>(x, Win, bin, xin);
    ntm_loop<<<64, 1024, 0, stream>>>(xin, h0, frf, fwf, m0,
        Wkr, bkr, Wbr, bbr, Wgr, bgr, Wkw, bkw, Wbw, bbw, Wgw, bgw,
        We, be, Wa, ba, Wread, bread, h_all);
    out_gemm<<<256, 256, 0, stream>>>(h_all, Wout, bout, (float*)d_out);
}

// Round 2
// 3177.104 us; speedup vs baseline: 1.0012x; 1.0012x over previous
//
#include <hip/hip_runtime.h>
#include <math.h>

#define B_   64
#define T_   128
#define NIN  256
#define H_   512
#define O_   256
#define M_   64
#define R_   512
#define EPS_ 1e-8f

__device__ __forceinline__ float dot4(float4 a, float4 b) {
    return a.x*b.x + a.y*b.y + a.z*b.z + a.w*b.w;
}

// 16-lane (DPP-row) sum reduction. Leaves the 16-lane sum in ALL 16 lanes.
template<int CTRL>
__device__ __forceinline__ float dpp_add(float v) {
    int t = __builtin_amdgcn_update_dpp(0, __float_as_int(v), CTRL, 0xF, 0xF, false);
    return v + __int_as_float(t);
}
__device__ __forceinline__ float red16(float v) {
    v = dpp_add<0xB1>(v);    // quad_perm xor1
    v = dpp_add<0x4E>(v);    // quad_perm xor2
    v = dpp_add<0x124>(v);   // row_ror:4
    v = dpp_add<0x128>(v);   // row_ror:8
    return v;
}
__device__ __forceinline__ float red64(float v) {
    v = red16(v);
    v += __shfl_xor(v, 16, 64);
    v += __shfl_xor(v, 32, 64);
    return v;
}
// fast transcendentals (native v_exp_f32 based), inf-safe
__device__ __forceinline__ float tanh_f(float x)    { float e = __expf(2.f * x); return 1.f - 2.f / (e + 1.f); }
__device__ __forceinline__ float sigmoid_f(float x) { return 1.f / (1.f + __expf(-x)); }
__device__ __forceinline__ float softplus_f(float x){ return x > 20.f ? x : log1pf(__expf(x)); }

// ---------------- Kernel 1: xin[bt][i] = x[bt] @ W_in.T + b_in ----------------
__global__ __launch_bounds__(256) void xin_gemm(
    const float* __restrict__ x, const float* __restrict__ Win,
    const float* __restrict__ bin, float* __restrict__ xin)
{
    __shared__ __align__(16) float xs[32 * NIN];
    const int tid  = threadIdx.x;
    const int row0 = blockIdx.x * 32;

    #pragma unroll
    for (int i = 0; i < 8; ++i) {
        int idx = i * 1024 + tid * 4;
        *(float4*)&xs[idx] = *(const float4*)&x[(size_t)row0 * NIN + idx];
    }
    __syncthreads();

    const int rg = tid >> 6;
    const int cg = tid & 63;
    const int c0 = cg * 8;
    float acc[8][8];
    #pragma unroll
    for (int r = 0; r < 8; ++r)
        #pragma unroll
        for (int c = 0; c < 8; ++c) acc[r][c] = 0.f;

    for (int k = 0; k < NIN; k += 4) {
        float4 xq[8];
        #pragma unroll
        for (int r = 0; r < 8; ++r) xq[r] = *(float4*)&xs[(rg * 8 + r) * NIN + k];
        #pragma unroll
        for (int c = 0; c < 8; ++c) {
            float4 w4 = *(const float4*)&Win[(size_t)(c0 + c) * NIN + k];
            #pragma unroll
            for (int r = 0; r < 8; ++r) acc[r][c] += dot4(xq[r], w4);
        }
    }
    #pragma unroll
    for (int r = 0; r < 8; ++r) {
        int grow = row0 + rg * 8 + r;
        #pragma unroll
        for (int c = 0; c < 8; ++c)
            xin[(size_t)grow * H_ + c0 + c] = acc[r][c] + bin[c0 + c];
    }
}

// ---------------- Kernel 2: recurrent loop, one WG per batch element ----------------
__global__ __launch_bounds__(1024, 4) void ntm_loop(
    const float* __restrict__ xin,
    const float* __restrict__ h0,
    const float* __restrict__ frf0, const float* __restrict__ fwf0,
    const float* __restrict__ m0,
    const float* __restrict__ Wkr, const float* __restrict__ bkr_g,
    const float* __restrict__ Wbr, const float* __restrict__ bbr_g,
    const float* __restrict__ Wgr, const float* __restrict__ bgr_g,
    const float* __restrict__ Wkw, const float* __restrict__ bkw_g,
    const float* __restrict__ Wbw, const float* __restrict__ bbw_g,
    const float* __restrict__ Wgw, const float* __restrict__ bgw_g,
    const float* __restrict__ We,  const float* __restrict__ be_g,
    const float* __restrict__ Wa,  const float* __restrict__ ba_g,
    const float* __restrict__ Wread, const float* __restrict__ bread_g,
    float* __restrict__ h_all)
{
    __shared__ __align__(16) float mem[R_ * M_];     // 128 KB, bank-spread for (g,sub) pattern
    __shared__ __align__(16) float hbuf[H_];
    __shared__ float frf2[2][R_];
    __shared__ float fwf2[2][R_];
    __shared__ float dotsR[R_];                      // holds exp() scores
    __shared__ float dotsW[R_];
    __shared__ float nrm2[R_];
    __shared__ float wread_s[R_];
    __shared__ float wwrite_s[R_];
    __shared__ __align__(16) float kR[M_];
    __shared__ __align__(16) float kW[M_];
    __shared__ __align__(16) float eV[M_];
    __shared__ __align__(16) float aV[M_];
    __shared__ __align__(16) float rt[M_];
    __shared__ float wsumR[16], wsumW[16];
    __shared__ float bias4[4 * M_];
    __shared__ float scal[8];   // 0:beta_r 1:g_r 2:beta_w 3:g_w 4:||kR||^2 5:||kW||^2

    const int b    = blockIdx.x;
    const int tid  = threadIdx.x;
    const int wave = tid >> 6, lane = tid & 63;
    const int g    = lane >> 4, sub = lane & 15;

    // ---- init: stage state ----
    const float* mg = m0 + (size_t)b * (R_ * M_);
    #pragma unroll
    for (int i = 0; i < 8; ++i) {
        int idx = i * 4096 + tid * 4;
        *(float4*)&mem[idx] = *(const float4*)&mg[idx];
    }
    if (tid < H_) hbuf[tid] = h0[b * H_ + tid];
    if (tid < R_) { frf2[0][tid] = frf0[b * R_ + tid]; fwf2[0][tid] = fwf0[b * R_ + tid]; }
    if (tid < M_) {
        bias4[tid]          = bkr_g[tid];
        bias4[M_ + tid]     = bkw_g[tid];
        bias4[2 * M_ + tid] = be_g[tid];
        bias4[3 * M_ + tid] = ba_g[tid];
    }
    if (tid == 1024 - 2) scal[4] = 0.f;
    if (tid == 1024 - 1) scal[5] = 0.f;
    __syncthreads();
    // initial row norms
    #pragma unroll
    for (int i = 0; i < 8; ++i) {
        int r = wave * 32 + i * 4 + g;
        float4 v = *(float4*)&mem[r * M_ + sub * 4];
        float np = v.x*v.x + v.y*v.y + v.z*v.z + v.w*v.w;
        np = red16(np);
        if (sub == 0) nrm2[r] = np;
    }
    __syncthreads();

    float hv_reg = 0.f;   // deferred h_all store value (tid<512)

    for (int t = 0; t < T_; ++t) {
        const int cur = t & 1, nxt = cur ^ 1;

        // ================= Phase A: projections + scalars + prefetch =================
        if (tid < M_) rt[tid] = 0.f;
        float xin_reg = 0.f;
        if (tid < H_) {
            if (t > 0) h_all[(size_t)(b * T_ + (t - 1)) * H_ + tid] = hv_reg;
            xin_reg = xin[(size_t)(b * T_ + t) * H_ + tid];
        }
        {
            const int row = tid >> 4, s16 = tid & 15;
            const int koff = s16 * 4;
            float a0 = 0, a1 = 0, a2 = 0, a3 = 0;
            const float* p0 = Wkr + row * H_ + koff;
            const float* p1 = Wkw + row * H_ + koff;
            const float* p2 = We  + row * H_ + koff;
            const float* p3 = Wa  + row * H_ + koff;
            #pragma unroll
            for (int j = 0; j < 8; ++j) {
                float4 h4 = *(float4*)&hbuf[j * 64 + koff];   // 2-way banks: free
                a0 += dot4(h4, *(const float4*)&p0[j * 64]);
                a1 += dot4(h4, *(const float4*)&p1[j * 64]);
                a2 += dot4(h4, *(const float4*)&p2[j * 64]);
                a3 += dot4(h4, *(const float4*)&p3[j * 64]);
            }
            a0 = red16(a0); a1 = red16(a1); a2 = red16(a2); a3 = red16(a3);
            if (s16 == 0) {
                float kv = tanh_f(a0 + bias4[row]);
                kR[row] = kv; atomicAdd(&scal[4], kv * kv);
            } else if (s16 == 1) {
                float kv = tanh_f(a1 + bias4[M_ + row]);
                kW[row] = kv; atomicAdd(&scal[5], kv * kv);
            } else if (s16 == 2) {
                eV[row] = sigmoid_f(a2 + bias4[2 * M_ + row]);
            } else if (s16 == 3) {
                aV[row] = tanh_f(a3 + bias4[3 * M_ + row]);
            }
            if (tid < 256) {   // 4 scalar heads, one wave each
                const int sc = tid >> 6;
                const float* Ws = sc == 0 ? Wbr : sc == 1 ? Wgr : sc == 2 ? Wbw : Wgw;
                const float* bs = sc == 0 ? bbr_g : sc == 1 ? bgr_g : sc == 2 ? bbw_g : bgw_g;
                float acc = 0;
                #pragma unroll
                for (int j = 0; j < 2; ++j) {
                    float4 h4 = *(float4*)&hbuf[lane * 8 + j * 4];
                    acc += dot4(h4, *(const float4*)&Ws[lane * 8 + j * 4]);
                }
                acc = red64(acc);
                if (lane == 0) {
                    float xv = acc + bs[0];
                    scal[sc] = (sc == 0 || sc == 2) ? softplus_f(xv) : sigmoid_f(xv);
                }
            }
        }
        __syncthreads();   // B1

        // ====== Phase B: content dots -> exp scores + per-wave partial sums ======
        {
            float4 kr4 = *(float4*)&kR[sub * 4];
            float4 kw4 = *(float4*)&kW[sub * 4];
            float snKR = sqrtf(scal[4]);
            float snKW = sqrtf(scal[5]);
            float beta_r = scal[0], beta_w = scal[2];
            float eaccR = 0.f, eaccW = 0.f;
            #pragma unroll
            for (int i = 0; i < 8; ++i) {
                int r = wave * 32 + i * 4 + g;
                float4 v = *(float4*)&mem[r * M_ + sub * 4];
                float dr = red16(dot4(kr4, v));
                float dw = red16(dot4(kw4, v));
                float sn = sqrtf(nrm2[r]);
                if (sub == 0) {
                    float e = __expf(beta_r * dr / (snKR * sn + EPS_));
                    dotsR[r] = e; eaccR += e;
                } else if (sub == 1) {
                    float e = __expf(beta_w * dw / (snKW * sn + EPS_));
                    dotsW[r] = e; eaccW += e;
                }
            }
            float vR = red64(sub == 0 ? eaccR : 0.f);
            float vW = red64(sub == 1 ? eaccW : 0.f);
            if (lane == 0) { wsumR[wave] = vR; wsumW[wave] = vW; }
        }
        __syncthreads();   // B2

        // ====== Phase C: filters (same-wave) + mem update + r_t partials + norms ======
        {
            if (lane < 32) {   // one row per lane; this wave's 32 rows
                const int r = wave * 32 + lane;
                float totR = 0, totW = 0;
                #pragma unroll
                for (int w2 = 0; w2 < 16; ++w2) { totR += wsumR[w2]; totW += wsumW[w2]; }
                float invR = 1.f / totR, invW = 1.f / totW;
                const int rm = (r + R_ - 1) & (R_ - 1), rp = (r + 1) & (R_ - 1);
                float gr = scal[1], gw = scal[3];

                float f0 = gr * dotsR[r]  * invR + (1.f - gr) * frf2[cur][r];
                float fm = gr * dotsR[rm] * invR + (1.f - gr) * frf2[cur][rm];
                float fp = gr * dotsR[rp] * invR + (1.f - gr) * frf2[cur][rp];
                frf2[nxt][r] = f0;
                wread_s[r] = 0.5f * f0 + 0.5f * (0.25f * fm + 0.5f * f0 + 0.25f * fp);

                float q0 = gw * dotsW[r]  * invW + (1.f - gw) * fwf2[cur][r];
                float qm = gw * dotsW[rm] * invW + (1.f - gw) * fwf2[cur][rm];
                float qp = gw * dotsW[rp] * invW + (1.f - gw) * fwf2[cur][rp];
                fwf2[nxt][r] = q0;
                wwrite_s[r] = 0.5f * q0 + 0.5f * (0.25f * qm + 0.5f * q0 + 0.25f * qp);
            }
            __builtin_amdgcn_wave_barrier();   // keep write->read order within wave

            float4 e4 = *(float4*)&eV[sub * 4];
            float4 a4 = *(float4*)&aV[sub * 4];
            float rt0 = 0, rt1 = 0, rt2 = 0, rt3 = 0;
            #pragma unroll
            for (int i = 0; i < 8; ++i) {
                int r = wave * 32 + i * 4 + g;
                float wr = wread_s[r], ww = wwrite_s[r];   // same-wave LDS, lgkmcnt-ordered
                float4 v = *(float4*)&mem[r * M_ + sub * 4];
                rt0 += wr * v.x; rt1 += wr * v.y; rt2 += wr * v.z; rt3 += wr * v.w;
                float4 nv;
                nv.x = v.x * (1.f - ww * e4.x) + ww * a4.x;
                nv.y = v.y * (1.f - ww * e4.y) + ww * a4.y;
                nv.z = v.z * (1.f - ww * e4.z) + ww * a4.z;
                nv.w = v.w * (1.f - ww * e4.w) + ww * a4.w;
                *(float4*)&mem[r * M_ + sub * 4] = nv;
                float np = nv.x*nv.x + nv.y*nv.y + nv.z*nv.z + nv.w*nv.w;
                np = red16(np);
                if (sub == 0) nrm2[r] = np;
            }
            rt0 += __shfl_xor(rt0, 16, 64); rt0 += __shfl_xor(rt0, 32, 64);
            rt1 += __shfl_xor(rt1, 16, 64); rt1 += __shfl_xor(rt1, 32, 64);
            rt2 += __shfl_xor(rt2, 16, 64); rt2 += __shfl_xor(rt2, 32, 64);
            rt3 += __shfl_xor(rt3, 16, 64); rt3 += __shfl_xor(rt3, 32, 64);
            if (g == 0) {
                atomicAdd(&rt[sub * 4 + 0], rt0);
                atomicAdd(&rt[sub * 4 + 1], rt1);
                atomicAdd(&rt[sub * 4 + 2], rt2);
                atomicAdd(&rt[sub * 4 + 3], rt3);
            }
        }
        __syncthreads();   // B3

        // ================= Phase D: h_{t+1} =================
        if (tid < H_) {
            float acc = bread_g[tid];
            const float* wr = Wread + tid * M_;
            #pragma unroll
            for (int j = 0; j < 16; ++j)
                acc += dot4(*(const float4*)&wr[j * 4], *(float4*)&rt[j * 4]);
            acc += xin_reg;
            hv_reg = fmaxf(acc, 0.f);
            hbuf[tid] = hv_reg;
        } else if (tid == H_) {
            scal[4] = 0.f;
        } else if (tid == H_ + 1) {
            scal[5] = 0.f;
        }
        __syncthreads();   // B4
    }

    if (tid < H_) h_all[(size_t)(b * T_ + (T_ - 1)) * H_ + tid] = hv_reg;
}

// ---------------- Kernel 3: out = sigmoid(h_all @ W_out.T + b_out) ----------------
__global__ __launch_bounds__(256) void out_gemm(
    const float* __restrict__ h_all, const float* __restrict__ Wout,
    const float* __restrict__ bout, float* __restrict__ out)
{
    __shared__ __align__(16) float hs[32 * H_];
    const int tid  = threadIdx.x;
    const int row0 = blockIdx.x * 32;

    #pragma unroll
    for (int i = 0; i < 16; ++i) {
        int idx = i * 1024 + tid * 4;
        *(float4*)&hs[idx] = *(const float4*)&h_all[(size_t)row0 * H_ + idx];
    }
    __syncthreads();

    const int rg = tid >> 6;
    const int cg = tid & 63;
    const int c0 = cg * 4;
    float acc[8][4];
    #pragma unroll
    for (int r = 0; r < 8; ++r)
        #pragma unroll
        for (int c = 0; c < 4; ++c) acc[r][c] = 0.f;

    for (int k = 0; k < H_; k += 4) {
        float4 xq[8];
        #pragma unroll
        for (int r = 0; r < 8; ++r) xq[r] = *(float4*)&hs[(rg * 8 + r) * H_ + k];
        #pragma unroll
        for (int c = 0; c < 4; ++c) {
            float4 w4 = *(const float4*)&Wout[(size_t)(c0 + c) * H_ + k];
            #pragma unroll
            for (int r = 0; r < 8; ++r) acc[r][c] += dot4(xq[r], w4);
        }
    }
    #pragma unroll
    for (int r = 0; r < 8; ++r) {
        int grow = row0 + rg * 8 + r;
        float4 o4;
        o4.x = sigmoid_f(acc[r][0] + bout[c0 + 0]);
        o4.y = sigmoid_f(acc[r][1] + bout[c0 + 1]);
        o4.z = sigmoid_f(acc[r][2] + bout[c0 + 2]);
        o4.w = sigmoid_f(acc[r][3] + bout[c0 + 3]);
        *(float4*)&out[(size_t)grow * O_ + c0] = o4;
    }
}

extern "C" void kernel_launch(void* const* d_in, const int* in_sizes, int n_in,
                              void* d_out, int out_size, void* d_ws, size_t ws_size,
                              hipStream_t stream) {
    const float* x     = (const float*)d_in[0];
    const float* h0    = (const float*)d_in[1];
    const float* frf   = (const float*)d_in[2];
    const float* fwf   = (const float*)d_in[4];
    const float* m0    = (const float*)d_in[6];
    const float* Win   = (const float*)d_in[7];
    const float* bin   = (const float*)d_in[8];
    const float* Wread = (const float*)d_in[9];
    const float* bread = (const float*)d_in[10];
    const float* Wout  = (const float*)d_in[11];
    const float* bout  = (const float*)d_in[12];
    const float* Wkr   = (const float*)d_in[13];
    const float* bkr   = (const float*)d_in[14];
    const float* Wbr   = (const float*)d_in[15];
    const float* bbr   = (const float*)d_in[16];
    const float* Wgr   = (const float*)d_in[17];
    const float* bgr   = (const float*)d_in[18];
    const float* Wkw   = (const float*)d_in[19];
    const float* bkw   = (const float*)d_in[20];
    const float* Wbw   = (const float*)d_in[21];
    const float* bbw   = (const float*)d_in[22];
    const float* Wgw   = (const float*)d_in[23];
    const float* bgw   = (const float*)d_in[24];
    const float* We    = (const float*)d_in[25];
    const float* be    = (const float*)d_in[26];
    const float* Wa    = (const float*)d_in[27];
    const float* ba    = (const float*)d_in[28];

    float* xin   = (float*)d_ws;
    float* h_all = (float*)((char*)d_ws + (size_t)B_ * T_ * H_ * 4);

    xin_gemm<<<256, 256, 0, stream>>>(x, Win, bin, xin);
    ntm_loop<<<64, 1024, 0, stream>>>(xin, h0, frf, fwf, m0,
        Wkr, bkr, Wbr, bbr, Wgr, bgr, Wkw, bkw, Wbw, bbw, Wgw, bgw,
        We, be, Wa, ba, Wread, bread, h_all);
    out_gemm<<<256, 256, 0, stream>>>(h_all, Wout, bout, (float*)d_out);
}